// Round 3
// baseline (583.116 us; speedup 1.0000x reference)
//
#include <hip/hip_runtime.h>
#include <stdint.h>

#define B_ROWS 32768
#define F_DIM  1024
#define H_DIM  512
#define RS     32832   // qkv_t row stride: B_ROWS + 64 floats, breaks 2^17 aliasing

typedef __attribute__((ext_vector_type(4))) float    floatx4;
typedef __attribute__((ext_vector_type(2))) __fp16   fp16x2;
typedef __attribute__((ext_vector_type(8))) _Float16 halfx8;

__device__ __forceinline__ void async_load16(const void* g, void* l) {
    __builtin_amdgcn_global_load_lds(
        (const __attribute__((address_space(1))) void*)g,
        (__attribute__((address_space(3))) void*)l, 16, 0, 0);
}

// --------------------------------------------------------------------------
// Wcomb[k,d,f] = sum_h Wqkv[k,d,h] * Wlin[k,h,f]   (d: 0-9 q, 10-19 k, 20-29 v)
// bcomb[k,d]   = b[k,d] + sum_h Wqkv[k,d,h] * blin[k,h]
// 4 blocks per (k,d), 64 threads each (256 f-cols per block). wrow/blin staged
// in LDS so the h-loop has no scalar-load dependency; dual accumulators break
// the serial FMA chain.
// --------------------------------------------------------------------------
__global__ __launch_bounds__(64) void k_prep(
    const float* __restrict__ Wlin, const float* __restrict__ blin,
    const float* __restrict__ Wq, const float* __restrict__ Wk,
    const float* __restrict__ Wv, const float* __restrict__ bq,
    const float* __restrict__ bk, const float* __restrict__ bv,
    ushort* __restrict__ Wcomb16, float* __restrict__ bcomb)
{
    __shared__ float sw_[H_DIM];
    __shared__ float sbl[H_DIM];
    const int bx = blockIdx.x;
    const int k  = bx >> 7;            // 0..3
    const int d  = (bx >> 2) & 31;     // 0..31
    const int qd = bx & 3;             // quarter
    const int t  = threadIdx.x;        // 0..63
    const int col = qd * 256 + t * 4;
    ushort4* outp = (ushort4*)(Wcomb16 + (((size_t)(k * 32 + d)) << 10) + col);

    if (d >= 30) {                     // pad rows: keep MFMA cols 30/31 finite
        ushort4 z; z.x = z.y = z.z = z.w = 0;
        *outp = z;
        if (qd == 0 && t == 0) bcomb[k * 32 + d] = 0.f;
        return;
    }

    const float* wrow; float bias;
    if (d < 10)      { wrow = Wq + (size_t)(k * 10 + d) * H_DIM;      bias = bq[k * 10 + d]; }
    else if (d < 20) { wrow = Wk + (size_t)(k * 10 + d - 10) * H_DIM; bias = bk[k * 10 + d - 10]; }
    else             { wrow = Wv + (size_t)(k * 10 + d - 20) * H_DIM; bias = bv[k * 10 + d - 20]; }

    const float* bl = blin + (size_t)k * H_DIM;
    for (int i = t; i < H_DIM; i += 64) { sw_[i] = wrow[i]; sbl[i] = bl[i]; }
    __syncthreads();

    const float* wl = Wlin + (((size_t)k * H_DIM) << 10) + col;

    floatx4 acc0 = {0.f,0.f,0.f,0.f}, acc1 = {0.f,0.f,0.f,0.f};
    float ba0 = 0.f, ba1 = 0.f;
    #pragma unroll 8
    for (int h = 0; h < H_DIM; h += 2) {
        const float s0 = sw_[h], s1 = sw_[h + 1];
        const floatx4 x0 = *(const floatx4*)(wl + ((size_t)h << 10));
        const floatx4 x1 = *(const floatx4*)(wl + ((size_t)(h + 1) << 10));
        acc0 += x0 * s0;
        acc1 += x1 * s1;
        ba0 += s0 * sbl[h];
        ba1 += s1 * sbl[h + 1];
    }
    const floatx4 acc = acc0 + acc1;
    union { _Float16 h[4]; ushort4 u; } o;
    o.h[0] = (_Float16)acc.x; o.h[1] = (_Float16)acc.y;
    o.h[2] = (_Float16)acc.z; o.h[3] = (_Float16)acc.w;
    *outp = o.u;
    if (qd == 0 && t == 0) bcomb[k * 32 + d] = bias + ba0 + ba1;
}

// --------------------------------------------------------------------------
// qkv_t[(k*30+d)*RS + b] = sum_f w_k[b,f] * Wcomb[k,d,f] + bcomb[k,d]
// A (the 512MB w stream) has ZERO reuse -> no LDS staging: each wave streams
// its 32 rows global->reg->cvt->MFMA, ping-pong buffered, barrier-free.
// B (Wcomb[k], 64KB f16) staged ONCE into LDS (XOR-swizzled) at kernel start.
// 512 threads (8 waves) x 256 rows per block; 512 blocks all resident.
// Heads 1..3 skip v (reference only uses att_out[:,0,:]).
// --------------------------------------------------------------------------
__global__ __launch_bounds__(512, 4) void k_main(
    const float* __restrict__ w0, const float* __restrict__ w1,
    const float* __restrict__ w2, const float* __restrict__ w3,
    const ushort* __restrict__ Wcomb16, const float* __restrict__ bcomb,
    float* __restrict__ qkv_t)
{
    __shared__ ushort Bs[32 * 1024];   // 64 KiB, whole Wcomb[k], swizzled slots

    const int tid     = threadIdx.x;
    const int bx      = blockIdx.x;
    const int k       = bx & 3;
    const int rowBase = (bx >> 2) * 256;

    const float* A = (k == 0) ? w0 : (k == 1) ? w1 : (k == 2) ? w2 : w3;

    // ---- one-shot B staging: 4096 16B slots; LDS dest linear, source slot
    // pre-swizzled so LDS[row][slot] = global[row][slot ^ (row&7)].
    #pragma unroll
    for (int it = 0; it < 8; ++it) {
        const int s   = it * 512 + tid;
        const int row = s >> 7;                   // 0..31
        const int g   = (s & 127) ^ (row & 7);    // source slot-in-row
        async_load16(Wcomb16 + (((size_t)(k * 32 + row)) << 10) + g * 8,
                     (ushort*)Bs + (size_t)s * 8);
    }
    __syncthreads();   // only barrier in the kernel (drains vmcnt)

    const int wv = tid >> 6;          // 0..7
    const int ln = tid & 63;
    const int lr = ln & 15;
    const int lq = ln >> 4;
    const int sw = lr & 7;            // B read-side swizzle key

    const float* aP0 = A + (size_t)(rowBase + wv * 32 + lr) * F_DIM + lq * 8;
    const float* aP1 = aP0 + (size_t)16 * F_DIM;

    floatx4 acc[2][2] = {};

#define LOADC(kc, b0, b1, b2, b3) do {                       \
    b0 = *(const floatx4*)(aP0 + (kc));                      \
    b1 = *(const floatx4*)(aP0 + (kc) + 4);                  \
    b2 = *(const floatx4*)(aP1 + (kc));                      \
    b3 = *(const floatx4*)(aP1 + (kc) + 4);                  \
} while (0)

#define COMPUTE(t, b0, b1, b2, b3) do {                                      \
    union { fp16x2 h2[4]; halfx8 h8; } u0, u1;                               \
    u0.h2[0] = __builtin_amdgcn_cvt_pkrtz(b0.x, b0.y);                       \
    u0.h2[1] = __builtin_amdgcn_cvt_pkrtz(b0.z, b0.w);                       \
    u0.h2[2] = __builtin_amdgcn_cvt_pkrtz(b1.x, b1.y);                       \
    u0.h2[3] = __builtin_amdgcn_cvt_pkrtz(b1.z, b1.w);                       \
    u1.h2[0] = __builtin_amdgcn_cvt_pkrtz(b2.x, b2.y);                       \
    u1.h2[1] = __builtin_amdgcn_cvt_pkrtz(b2.z, b2.w);                       \
    u1.h2[2] = __builtin_amdgcn_cvt_pkrtz(b3.x, b3.y);                       \
    u1.h2[3] = __builtin_amdgcn_cvt_pkrtz(b3.z, b3.w);                       \
    const int slot_ = (((t) * 4 + lq) ^ sw) * 8;                             \
    const halfx8 bf0 = *(const halfx8*)&Bs[(lr << 10) + slot_];              \
    const halfx8 bf1 = *(const halfx8*)&Bs[((16 + lr) << 10) + slot_];       \
    acc[0][0] = __builtin_amdgcn_mfma_f32_16x16x32_f16(u0.h8, bf0, acc[0][0], 0, 0, 0); \
    acc[0][1] = __builtin_amdgcn_mfma_f32_16x16x32_f16(u0.h8, bf1, acc[0][1], 0, 0, 0); \
    acc[1][0] = __builtin_amdgcn_mfma_f32_16x16x32_f16(u1.h8, bf0, acc[1][0], 0, 0, 0); \
    acc[1][1] = __builtin_amdgcn_mfma_f32_16x16x32_f16(u1.h8, bf1, acc[1][1], 0, 0, 0); \
} while (0)

    floatx4 a0, a1, a2, a3, c0, c1, c2, c3;
    LOADC(0, a0, a1, a2, a3);
    #pragma unroll 2
    for (int t = 0; t < 32; t += 2) {
        LOADC((t + 1) * 32, c0, c1, c2, c3);
        COMPUTE(t, a0, a1, a2, a3);
        if (t + 2 < 32) LOADC((t + 2) * 32, a0, a1, a2, a3);
        COMPUTE(t + 1, c0, c1, c2, c3);
    }
#undef LOADC
#undef COMPUTE

    // epilogue: +bcomb, store transposed (padded stride RS).
    // C/D: col=lane&15 (-> d = j*16+lr), row=(lane>>4)*4+reg (-> b).
    const float* bc   = bcomb + k * 32;
    const int    dmax = (k == 0) ? 30 : 20;   // v only needed for head 0
    #pragma unroll
    for (int j = 0; j < 2; ++j) {
        const int d = j * 16 + lr;
        if (d < dmax) {
            const float bias = bc[d];
            float* outd = qkv_t + (size_t)(k * 30 + d) * RS;
            #pragma unroll
            for (int i = 0; i < 2; ++i) {
                const int r0 = rowBase + wv * 32 + i * 16 + lq * 4;
                floatx4 o = acc[i][j];
                o.x += bias; o.y += bias; o.z += bias; o.w += bias;
                *(floatx4*)(outd + r0) = o;
            }
        }
    }
}

// -------------------------------------------- per-b attention + heads epilogue
// attn staged in LDS (padded x101: conflict-free), written back fully
// coalesced (512B per wave-instruction). Same for outputs.
__global__ __launch_bounds__(128) void k_final(
    const float* __restrict__ qkv_t, const float* __restrict__ Wfin,
    const float* __restrict__ bfin,
    float* __restrict__ outputs, float* __restrict__ attn)
{
    __shared__ float sW[400];
    __shared__ float sb[40];
    __shared__ float sA[128 * 101];   // 50.5 KiB attn staging, +1 pad
    const int t = threadIdx.x;
    for (int i = t; i < 400; i += 128) sW[i] = Wfin[i];
    if (t < 40) sb[t] = bfin[t];
    __syncthreads();

    const int b = blockIdx.x * 128 + t;
    const float* pt = qkv_t + b;                     // coalesced column reads
    float q[4][10], kk[4][10], v0[10];
    #pragma unroll
    for (int k = 0; k < 4; ++k)
        #pragma unroll
        for (int e = 0; e < 10; ++e) {
            q[k][e]  = pt[(size_t)(k * 30 + e) * RS];
            kk[k][e] = pt[(size_t)(k * 30 + 10 + e) * RS];
        }
    #pragma unroll
    for (int m = 0; m < 10; ++m) v0[m] = pt[(size_t)(20 + m) * RS];  // v, head 0

    float out0[10];
    #pragma unroll
    for (int e = 0; e < 10; ++e) out0[e] = 0.f;
    float* sAr = &sA[t * 101];
    const float inv = 0.31622776601683794f;  // 1/sqrt(10)

    // attn[b,e,m] = softmax over e (axis=1) of (sum_k q[k][e]*kk[k][m])/sqrt(E)
    #pragma unroll
    for (int m = 0; m < 10; ++m) {
        float col[10]; float mx = -1e30f;
        #pragma unroll
        for (int e = 0; e < 10; ++e) {
            col[e] = (q[0][e]*kk[0][m] + q[1][e]*kk[1][m]
                    + q[2][e]*kk[2][m] + q[3][e]*kk[3][m]) * inv;
            mx = fmaxf(mx, col[e]);
        }
        float s = 0.f;
        #pragma unroll
        for (int e = 0; e < 10; ++e) { col[e] = __expf(col[e] - mx); s += col[e]; }
        const float r = 1.f / s;
        #pragma unroll
        for (int e = 0; e < 10; ++e) {
            const float a = col[e] * r;
            sAr[e * 10 + m] = a;
            out0[e] += a * v0[m];     // att_out[b,0,e] accumulation
        }
    }

    float oc[10];
    #pragma unroll
    for (int c = 0; c < 10; ++c) oc[c] = 0.f;
    #pragma unroll
    for (int k = 0; k < 4; ++k) {
        float lg[10]; float mx = -1e30f;
        #pragma unroll
        for (int c = 0; c < 10; ++c) {
            float s = sb[k * 10 + c];
            #pragma unroll
            for (int e = 0; e < 10; ++e) s += out0[e] * sW[(k * 10 + c) * 10 + e];
            lg[c] = s; mx = fmaxf(mx, s);
        }
        float s = 0.f;
        #pragma unroll
        for (int c = 0; c < 10; ++c) { lg[c] = __expf(lg[c] - mx); s += lg[c]; }
        const float r = 0.25f / s;
        #pragma unroll
        for (int c = 0; c < 10; ++c) oc[c] += lg[c] * r;
    }

    // ---- coalesced attn writeback: block tile = 128 b x 100 = 12800 floats
    __syncthreads();
    const size_t abase = (size_t)blockIdx.x * 12800;
    for (int i = t; i < 12800; i += 128) {
        const int bl = i / 100;                  // const-div -> magic mul
        attn[abase + i] = sA[bl * 101 + (i - bl * 100)];
    }

    // ---- coalesced outputs writeback: 128 b x 10 = 1280 floats
    __syncthreads();
    #pragma unroll
    for (int c = 0; c < 10; ++c) sA[t * 11 + c] = oc[c];
    __syncthreads();
    const size_t obase = (size_t)blockIdx.x * 1280;
    for (int i = t; i < 1280; i += 128) {
        const int bl = i / 10;
        outputs[obase + i] = sA[bl * 11 + (i - bl * 10)];
    }
}

extern "C" void kernel_launch(void* const* d_in, const int* in_sizes, int n_in,
                              void* d_out, int out_size, void* d_ws, size_t ws_size,
                              hipStream_t stream) {
    const float* w0   = (const float*)d_in[0];
    const float* w1   = (const float*)d_in[1];
    const float* w2   = (const float*)d_in[2];
    const float* w3   = (const float*)d_in[3];
    const float* Wlin = (const float*)d_in[4];
    const float* blin = (const float*)d_in[5];
    const float* Wq   = (const float*)d_in[6];
    const float* bq   = (const float*)d_in[7];
    const float* Wk   = (const float*)d_in[8];
    const float* bk   = (const float*)d_in[9];
    const float* Wv   = (const float*)d_in[10];
    const float* bv   = (const float*)d_in[11];
    const float* Wfin = (const float*)d_in[12];
    const float* bfin = (const float*)d_in[13];

    char* ws = (char*)d_ws;
    ushort* Wcomb16 = (ushort*)ws;                          // 256 KiB  [4][32][1024] f16
    float*  bcomb   = (float*)(ws + ((size_t)256 << 10));   // 512 B    [4][32]
    float*  qkv_t   = (float*)(ws + ((size_t)1 << 20));     // ~15.8 MiB [120][RS]

    float* outputs = (float*)d_out;
    float* attn    = outputs + (size_t)B_ROWS * 10;

    k_prep <<<512, 64,  0, stream>>>(Wlin, blin, Wq, Wk, Wv, bq, bk, bv, Wcomb16, bcomb);
    k_main <<<512, 512, 0, stream>>>(w0, w1, w2, w3, Wcomb16, bcomb, qkv_t);
    k_final<<<256, 128, 0, stream>>>(qkv_t, Wfin, bfin, outputs, attn);
}

// Round 4
// 566.883 us; speedup vs baseline: 1.0286x; 1.0286x over previous
//
#include <hip/hip_runtime.h>
#include <stdint.h>

#define B_ROWS 32768
#define F_DIM  1024
#define H_DIM  512

typedef __attribute__((ext_vector_type(4))) float    floatx4;
typedef __attribute__((ext_vector_type(2))) __fp16   fp16x2;
typedef __attribute__((ext_vector_type(8))) _Float16 halfx8;

__device__ __forceinline__ void async_load16(const void* g, void* l) {
    __builtin_amdgcn_global_load_lds(
        (const __attribute__((address_space(1))) void*)g,
        (__attribute__((address_space(3))) void*)l, 16, 0, 0);
}

// --------------------------------------------------------------------------
// Wcomb[k,d,f] = sum_h Wqkv[k,d,h] * Wlin[k,h,f]   (d: 0-9 q, 10-19 k, 20-29 v)
// bcomb[k,d]   = b[k,d] + sum_h Wqkv[k,d,h] * blin[k,h]
// 2 blocks per (k,d) x 128 thr (round-2 shape). wrow/blin staged in LDS,
// dual accumulators break the serial FMA chain.
// --------------------------------------------------------------------------
__global__ __launch_bounds__(128) void k_prep(
    const float* __restrict__ Wlin, const float* __restrict__ blin,
    const float* __restrict__ Wq, const float* __restrict__ Wk,
    const float* __restrict__ Wv, const float* __restrict__ bq,
    const float* __restrict__ bk, const float* __restrict__ bv,
    ushort* __restrict__ Wcomb16, float* __restrict__ bcomb)
{
    __shared__ float sw_[H_DIM];
    __shared__ float sbl[H_DIM];
    const int bx   = blockIdx.x;
    const int k    = bx >> 6;           // 0..3
    const int d    = (bx >> 1) & 31;    // 0..31
    const int half = bx & 1;
    const int t    = threadIdx.x;       // 0..127
    const int col  = half * 512 + t * 4;
    ushort4* outp = (ushort4*)(Wcomb16 + (((size_t)(k * 32 + d)) << 10) + col);

    if (d >= 30) {                      // pad rows (whole block uniform)
        ushort4 z; z.x = z.y = z.z = z.w = 0;
        *outp = z;
        if (half == 0 && t == 0) bcomb[k * 32 + d] = 0.f;
        return;
    }

    const float* wrow; float bias;
    if (d < 10)      { wrow = Wq + (size_t)(k * 10 + d) * H_DIM;      bias = bq[k * 10 + d]; }
    else if (d < 20) { wrow = Wk + (size_t)(k * 10 + d - 10) * H_DIM; bias = bk[k * 10 + d - 10]; }
    else             { wrow = Wv + (size_t)(k * 10 + d - 20) * H_DIM; bias = bv[k * 10 + d - 20]; }

    const float* bl = blin + (size_t)k * H_DIM;
    for (int i = t; i < H_DIM; i += 128) { sw_[i] = wrow[i]; sbl[i] = bl[i]; }
    __syncthreads();

    const float* wl = Wlin + (((size_t)k * H_DIM) << 10) + col;

    floatx4 acc0 = {0.f,0.f,0.f,0.f}, acc1 = {0.f,0.f,0.f,0.f};
    float ba0 = 0.f, ba1 = 0.f;
    #pragma unroll 8
    for (int h = 0; h < H_DIM; h += 2) {
        const float s0 = sw_[h], s1 = sw_[h + 1];
        const floatx4 x0 = *(const floatx4*)(wl + ((size_t)h << 10));
        const floatx4 x1 = *(const floatx4*)(wl + ((size_t)(h + 1) << 10));
        acc0 += x0 * s0;
        acc1 += x1 * s1;
        ba0 += s0 * sbl[h];
        ba1 += s1 * sbl[h + 1];
    }
    const floatx4 acc = acc0 + acc1;
    union { _Float16 h[4]; ushort4 u; } o;
    o.h[0] = (_Float16)acc.x; o.h[1] = (_Float16)acc.y;
    o.h[2] = (_Float16)acc.z; o.h[3] = (_Float16)acc.w;
    *outp = o.u;
    if (half == 0 && t == 0) bcomb[k * 32 + d] = bias + ba0 + ba1;
}

// --------------------------------------------------------------------------
// FUSED: qkv (MFMA, per-head) -> LDS -> attention + heads epilogue.
// Block = 128 b-rows, 512 threads (8 waves, 16 rows each). Per head k:
//   stage Wcomb[k] (64KB f16, slot-swizzled) -> barrier ->
//   reg-stream A rows (ping-pong, verified R3 pattern) -> 2 MFMA/k-step ->
//   +bias -> QKV LDS tile [128][121].
// Then threads 0-127 run attention math from LDS; attn/outputs staged in LDS
// (overlaying the dead Bs region) and written fully coalesced.
// qkv_t global round-trip and the third kernel are eliminated.
// --------------------------------------------------------------------------
#define SM_BS    0                        // 64 KiB  ushort[32*1024]
#define SM_QKV   (64 * 1024)              // 61.9 KiB float[128*121]
#define SM_BC    (SM_QKV + 128 * 121 * 4) // 512 B   float[128]
#define SM_W     (SM_BC + 512)            // 1600 B  float[400]
#define SM_B     (SM_W + 1600)            // 160 B   float[40]
#define SM_TOTAL (SM_B + 160)             // 129,824 B

__global__ __launch_bounds__(512) void k_all(
    const float* __restrict__ w0, const float* __restrict__ w1,
    const float* __restrict__ w2, const float* __restrict__ w3,
    const ushort* __restrict__ Wcomb16, const float* __restrict__ bcomb,
    const float* __restrict__ Wfin, const float* __restrict__ bfin,
    float* __restrict__ outputs, float* __restrict__ attn)
{
    __shared__ __align__(16) unsigned char smem[SM_TOTAL];
    ushort* Bs  = (ushort*)(smem + SM_BS);
    float*  QKV = (float*) (smem + SM_QKV);   // [128][121]
    float*  sbc = (float*) (smem + SM_BC);
    float*  sW  = (float*) (smem + SM_W);
    float*  sb  = (float*) (smem + SM_B);
    float*  sA  = (float*) (smem + SM_BS);    // overlay after heads: [128][101]

    const int tid     = threadIdx.x;
    const int rowBase = blockIdx.x * 128;

    if (tid < 128) sbc[tid] = bcomb[tid];
    if (tid < 400) sW[tid]  = Wfin[tid];
    if (tid < 40)  sb[tid]  = bfin[tid];

    const int wv = tid >> 6;          // 0..7
    const int ln = tid & 63;
    const int lr = ln & 15;
    const int lq = ln >> 4;
    const int sw = lr & 7;            // Bs read-side swizzle key

    #pragma unroll 1
    for (int k = 0; k < 4; ++k) {
        const float* A = (k == 0) ? w0 : (k == 1) ? w1 : (k == 2) ? w2 : w3;

        __syncthreads();              // prior head done reading Bs (k=0: constants visible)
        #pragma unroll
        for (int it = 0; it < 8; ++it) {
            const int s   = it * 512 + tid;           // 16B slot 0..4095
            const int row = s >> 7;                   // 0..31
            const int g   = (s & 127) ^ (row & 7);    // source slot-in-row
            async_load16(Wcomb16 + (((size_t)(k * 32 + row)) << 10) + g * 8,
                         (ushort*)Bs + (size_t)s * 8);
        }
        __syncthreads();              // drains vmcnt: Bs ready

        const float* aP = A + (size_t)(rowBase + wv * 16 + lr) * F_DIM + lq * 8;

        floatx4 acc0 = {0.f,0.f,0.f,0.f};
        floatx4 acc1 = {0.f,0.f,0.f,0.f};

#define COMPUTE(t, b0, b1) do {                                              \
    union { fp16x2 h2[4]; halfx8 h8; } u;                                    \
    u.h2[0] = __builtin_amdgcn_cvt_pkrtz(b0.x, b0.y);                        \
    u.h2[1] = __builtin_amdgcn_cvt_pkrtz(b0.z, b0.w);                        \
    u.h2[2] = __builtin_amdgcn_cvt_pkrtz(b1.x, b1.y);                        \
    u.h2[3] = __builtin_amdgcn_cvt_pkrtz(b1.z, b1.w);                        \
    const int slot_ = (((t) * 4 + lq) ^ sw) * 8;                             \
    const halfx8 bf0 = *(const halfx8*)&Bs[(lr << 10) + slot_];              \
    const halfx8 bf1 = *(const halfx8*)&Bs[((16 + lr) << 10) + slot_];       \
    acc0 = __builtin_amdgcn_mfma_f32_16x16x32_f16(u.h8, bf0, acc0, 0, 0, 0); \
    acc1 = __builtin_amdgcn_mfma_f32_16x16x32_f16(u.h8, bf1, acc1, 0, 0, 0); \
} while (0)

        floatx4 a0, a1, c0, c1;
        a0 = *(const floatx4*)(aP);
        a1 = *(const floatx4*)(aP + 4);
        #pragma unroll 4
        for (int t = 0; t < 32; t += 2) {
            c0 = *(const floatx4*)(aP + (t + 1) * 32);
            c1 = *(const floatx4*)(aP + (t + 1) * 32 + 4);
            COMPUTE(t, a0, a1);
            if (t + 2 < 32) {
                a0 = *(const floatx4*)(aP + (t + 2) * 32);
                a1 = *(const floatx4*)(aP + (t + 2) * 32 + 4);
            }
            COMPUTE(t + 1, c0, c1);
        }
#undef COMPUTE

        // QKV tile write. C/D: col(d)=lane&15 (+16j), row=(lane>>4)*4+reg.
        const int r0 = wv * 16 + lq * 4;
        #pragma unroll
        for (int r = 0; r < 4; ++r)
            QKV[(r0 + r) * 121 + k * 30 + lr] = acc0[r] + sbc[k * 32 + lr];
        const int d1 = 16 + lr;
        if (d1 < ((k == 0) ? 30 : 20)) {   // v only needed for head 0
            #pragma unroll
            for (int r = 0; r < 4; ++r)
                QKV[(r0 + r) * 121 + k * 30 + d1] = acc1[r] + sbc[k * 32 + d1];
        }
    }
    __syncthreads();   // QKV complete; Bs dead from here (sA overlays it)

    // ---------------- attention + heads epilogue (threads 0-127, 1 b-row each)
    float oc[10];
    if (tid < 128) {
        const float* Q = &QKV[tid * 121];
        float q[4][10], kk[4][10], v0[10];
        #pragma unroll
        for (int k = 0; k < 4; ++k)
            #pragma unroll
            for (int e = 0; e < 10; ++e) {
                q[k][e]  = Q[k * 30 + e];
                kk[k][e] = Q[k * 30 + 10 + e];
            }
        #pragma unroll
        for (int m = 0; m < 10; ++m) v0[m] = Q[20 + m];   // v, head 0

        float out0[10];
        #pragma unroll
        for (int e = 0; e < 10; ++e) out0[e] = 0.f;
        float* sAr = &sA[tid * 101];
        const float inv = 0.31622776601683794f;  // 1/sqrt(10)

        #pragma unroll
        for (int m = 0; m < 10; ++m) {
            float col[10]; float mx = -1e30f;
            #pragma unroll
            for (int e = 0; e < 10; ++e) {
                col[e] = (q[0][e]*kk[0][m] + q[1][e]*kk[1][m]
                        + q[2][e]*kk[2][m] + q[3][e]*kk[3][m]) * inv;
                mx = fmaxf(mx, col[e]);
            }
            float s = 0.f;
            #pragma unroll
            for (int e = 0; e < 10; ++e) { col[e] = __expf(col[e] - mx); s += col[e]; }
            const float r = 1.f / s;
            #pragma unroll
            for (int e = 0; e < 10; ++e) {
                const float a = col[e] * r;
                sAr[e * 10 + m] = a;
                out0[e] += a * v0[m];
            }
        }

        #pragma unroll
        for (int c = 0; c < 10; ++c) oc[c] = 0.f;
        #pragma unroll
        for (int k = 0; k < 4; ++k) {
            float lg[10]; float mx = -1e30f;
            #pragma unroll
            for (int c = 0; c < 10; ++c) {
                float s = sb[k * 10 + c];
                #pragma unroll
                for (int e = 0; e < 10; ++e) s += out0[e] * sW[(k * 10 + c) * 10 + e];
                lg[c] = s; mx = fmaxf(mx, s);
            }
            float s = 0.f;
            #pragma unroll
            for (int c = 0; c < 10; ++c) { lg[c] = __expf(lg[c] - mx); s += lg[c]; }
            const float r = 0.25f / s;
            #pragma unroll
            for (int c = 0; c < 10; ++c) oc[c] += lg[c] * r;
        }
    }

    // ---- coalesced attn writeback: 128 b x 100 = 12800 floats
    __syncthreads();
    const size_t abase = (size_t)blockIdx.x * 12800;
    for (int i = tid; i < 12800; i += 512) {
        const int bl = i / 100;
        attn[abase + i] = sA[bl * 101 + (i - bl * 100)];
    }

    // ---- coalesced outputs writeback: 128 b x 10 = 1280 floats
    __syncthreads();
    if (tid < 128) {
        #pragma unroll
        for (int c = 0; c < 10; ++c) sA[tid * 11 + c] = oc[c];
    }
    __syncthreads();
    const size_t obase = (size_t)blockIdx.x * 1280;
    for (int i = tid; i < 1280; i += 512) {
        const int bl = i / 10;
        outputs[obase + i] = sA[bl * 11 + (i - bl * 10)];
    }
}

extern "C" void kernel_launch(void* const* d_in, const int* in_sizes, int n_in,
                              void* d_out, int out_size, void* d_ws, size_t ws_size,
                              hipStream_t stream) {
    const float* w0   = (const float*)d_in[0];
    const float* w1   = (const float*)d_in[1];
    const float* w2   = (const float*)d_in[2];
    const float* w3   = (const float*)d_in[3];
    const float* Wlin = (const float*)d_in[4];
    const float* blin = (const float*)d_in[5];
    const float* Wq   = (const float*)d_in[6];
    const float* bq   = (const float*)d_in[7];
    const float* Wk   = (const float*)d_in[8];
    const float* bk   = (const float*)d_in[9];
    const float* Wv   = (const float*)d_in[10];
    const float* bv   = (const float*)d_in[11];
    const float* Wfin = (const float*)d_in[12];
    const float* bfin = (const float*)d_in[13];

    char* ws = (char*)d_ws;
    ushort* Wcomb16 = (ushort*)ws;                          // 256 KiB  [4][32][1024] f16
    float*  bcomb   = (float*)(ws + ((size_t)256 << 10));   // 512 B    [4][32]

    float* outputs = (float*)d_out;
    float* attn    = outputs + (size_t)B_ROWS * 10;

    k_prep<<<256, 128, 0, stream>>>(Wlin, blin, Wq, Wk, Wv, bq, bk, bv, Wcomb16, bcomb);
    k_all <<<256, 512, 0, stream>>>(w0, w1, w2, w3, Wcomb16, bcomb, Wfin, bfin, outputs, attn);
}

// Round 5
// 547.494 us; speedup vs baseline: 1.0651x; 1.0354x over previous
//
#include <hip/hip_runtime.h>
#include <stdint.h>

#define B_ROWS 32768
#define F_DIM  1024
#define H_DIM  512

typedef __attribute__((ext_vector_type(4))) float    floatx4;
typedef __attribute__((ext_vector_type(2))) __fp16   fp16x2;
typedef __attribute__((ext_vector_type(8))) _Float16 halfx8;

__device__ __forceinline__ void async_load16(const void* g, void* l) {
    __builtin_amdgcn_global_load_lds(
        (const __attribute__((address_space(1))) void*)g,
        (__attribute__((address_space(3))) void*)l, 16, 0, 0);
}

// Non-temporal 16B load: no L2/L3 allocation. In steady state the 512MB w
// stream then never occupies Infinity Cache -> all reads are clean HBM
// misses instead of a 50/50 HBM/L3-thrash mix (probe for the ~3TB/s wall).
__device__ __forceinline__ floatx4 nt_load4(const float* p) {
    return __builtin_nontemporal_load((const floatx4*)p);
}

// --------------------------------------------------------------------------
// Wcomb[k,d,f] = sum_h Wqkv[k,d,h] * Wlin[k,h,f]   (d: 0-9 q, 10-19 k, 20-29 v)
// bcomb[k,d]   = b[k,d] + sum_h Wqkv[k,d,h] * blin[k,h]
// 2 blocks per (k,d) x 128 thr. wrow/blin staged in LDS, dual accumulators.
// --------------------------------------------------------------------------
__global__ __launch_bounds__(128) void k_prep(
    const float* __restrict__ Wlin, const float* __restrict__ blin,
    const float* __restrict__ Wq, const float* __restrict__ Wk,
    const float* __restrict__ Wv, const float* __restrict__ bq,
    const float* __restrict__ bk, const float* __restrict__ bv,
    ushort* __restrict__ Wcomb16, float* __restrict__ bcomb)
{
    __shared__ float sw_[H_DIM];
    __shared__ float sbl[H_DIM];
    const int bx   = blockIdx.x;
    const int k    = bx >> 6;           // 0..3
    const int d    = (bx >> 1) & 31;    // 0..31
    const int half = bx & 1;
    const int t    = threadIdx.x;       // 0..127
    const int col  = half * 512 + t * 4;
    ushort4* outp = (ushort4*)(Wcomb16 + (((size_t)(k * 32 + d)) << 10) + col);

    if (d >= 30) {                      // pad rows (whole block uniform)
        ushort4 z; z.x = z.y = z.z = z.w = 0;
        *outp = z;
        if (half == 0 && t == 0) bcomb[k * 32 + d] = 0.f;
        return;
    }

    const float* wrow; float bias;
    if (d < 10)      { wrow = Wq + (size_t)(k * 10 + d) * H_DIM;      bias = bq[k * 10 + d]; }
    else if (d < 20) { wrow = Wk + (size_t)(k * 10 + d - 10) * H_DIM; bias = bk[k * 10 + d - 10]; }
    else             { wrow = Wv + (size_t)(k * 10 + d - 20) * H_DIM; bias = bv[k * 10 + d - 20]; }

    const float* bl = blin + (size_t)k * H_DIM;
    for (int i = t; i < H_DIM; i += 128) { sw_[i] = wrow[i]; sbl[i] = bl[i]; }
    __syncthreads();

    const float* wl = Wlin + (((size_t)k * H_DIM) << 10) + col;

    floatx4 acc0 = {0.f,0.f,0.f,0.f}, acc1 = {0.f,0.f,0.f,0.f};
    float ba0 = 0.f, ba1 = 0.f;
    #pragma unroll 8
    for (int h = 0; h < H_DIM; h += 2) {
        const float s0 = sw_[h], s1 = sw_[h + 1];
        const floatx4 x0 = *(const floatx4*)(wl + ((size_t)h << 10));
        const floatx4 x1 = *(const floatx4*)(wl + ((size_t)(h + 1) << 10));
        acc0 += x0 * s0;
        acc1 += x1 * s1;
        ba0 += s0 * sbl[h];
        ba1 += s1 * sbl[h + 1];
    }
    const floatx4 acc = acc0 + acc1;
    union { _Float16 h[4]; ushort4 u; } o;
    o.h[0] = (_Float16)acc.x; o.h[1] = (_Float16)acc.y;
    o.h[2] = (_Float16)acc.z; o.h[3] = (_Float16)acc.w;
    *outp = o.u;
    if (half == 0 && t == 0) bcomb[k * 32 + d] = bias + ba0 + ba1;
}

// --------------------------------------------------------------------------
// FUSED: qkv (MFMA, per-head) -> LDS -> attention + heads epilogue.
// Identical to round-4 k_all EXCEPT: the A (w) stream uses non-temporal
// loads (no L2/L3 allocation) -- single-variable A/B probe.
// --------------------------------------------------------------------------
#define SM_BS    0                        // 64 KiB  ushort[32*1024]
#define SM_QKV   (64 * 1024)              // 61.9 KiB float[128*121]
#define SM_BC    (SM_QKV + 128 * 121 * 4) // 512 B   float[128]
#define SM_W     (SM_BC + 512)            // 1600 B  float[400]
#define SM_B     (SM_W + 1600)            // 160 B   float[40]
#define SM_TOTAL (SM_B + 160)             // 129,824 B

__global__ __launch_bounds__(512) void k_all(
    const float* __restrict__ w0, const float* __restrict__ w1,
    const float* __restrict__ w2, const float* __restrict__ w3,
    const ushort* __restrict__ Wcomb16, const float* __restrict__ bcomb,
    const float* __restrict__ Wfin, const float* __restrict__ bfin,
    float* __restrict__ outputs, float* __restrict__ attn)
{
    __shared__ __align__(16) unsigned char smem[SM_TOTAL];
    ushort* Bs  = (ushort*)(smem + SM_BS);
    float*  QKV = (float*) (smem + SM_QKV);   // [128][121]
    float*  sbc = (float*) (smem + SM_BC);
    float*  sW  = (float*) (smem + SM_W);
    float*  sb  = (float*) (smem + SM_B);
    float*  sA  = (float*) (smem + SM_BS);    // overlay after heads: [128][101]

    const int tid     = threadIdx.x;
    const int rowBase = blockIdx.x * 128;

    if (tid < 128) sbc[tid] = bcomb[tid];
    if (tid < 400) sW[tid]  = Wfin[tid];
    if (tid < 40)  sb[tid]  = bfin[tid];

    const int wv = tid >> 6;          // 0..7
    const int ln = tid & 63;
    const int lr = ln & 15;
    const int lq = ln >> 4;
    const int sw = lr & 7;            // Bs read-side swizzle key

    #pragma unroll 1
    for (int k = 0; k < 4; ++k) {
        const float* A = (k == 0) ? w0 : (k == 1) ? w1 : (k == 2) ? w2 : w3;

        __syncthreads();              // prior head done reading Bs
        #pragma unroll
        for (int it = 0; it < 8; ++it) {
            const int s   = it * 512 + tid;           // 16B slot 0..4095
            const int row = s >> 7;                   // 0..31
            const int g   = (s & 127) ^ (row & 7);    // source slot-in-row
            async_load16(Wcomb16 + (((size_t)(k * 32 + row)) << 10) + g * 8,
                         (ushort*)Bs + (size_t)s * 8);
        }
        __syncthreads();              // drains vmcnt: Bs ready

        const float* aP = A + (size_t)(rowBase + wv * 16 + lr) * F_DIM + lq * 8;

        floatx4 acc0 = {0.f,0.f,0.f,0.f};
        floatx4 acc1 = {0.f,0.f,0.f,0.f};

#define COMPUTE(t, b0, b1) do {                                              \
    union { fp16x2 h2[4]; halfx8 h8; } u;                                    \
    u.h2[0] = __builtin_amdgcn_cvt_pkrtz(b0.x, b0.y);                        \
    u.h2[1] = __builtin_amdgcn_cvt_pkrtz(b0.z, b0.w);                        \
    u.h2[2] = __builtin_amdgcn_cvt_pkrtz(b1.x, b1.y);                        \
    u.h2[3] = __builtin_amdgcn_cvt_pkrtz(b1.z, b1.w);                        \
    const int slot_ = (((t) * 4 + lq) ^ sw) * 8;                             \
    const halfx8 bf0 = *(const halfx8*)&Bs[(lr << 10) + slot_];              \
    const halfx8 bf1 = *(const halfx8*)&Bs[((16 + lr) << 10) + slot_];       \
    acc0 = __builtin_amdgcn_mfma_f32_16x16x32_f16(u.h8, bf0, acc0, 0, 0, 0); \
    acc1 = __builtin_amdgcn_mfma_f32_16x16x32_f16(u.h8, bf1, acc1, 0, 0, 0); \
} while (0)

        floatx4 a0, a1, c0, c1;
        a0 = nt_load4(aP);
        a1 = nt_load4(aP + 4);
        #pragma unroll 4
        for (int t = 0; t < 32; t += 2) {
            c0 = nt_load4(aP + (t + 1) * 32);
            c1 = nt_load4(aP + (t + 1) * 32 + 4);
            COMPUTE(t, a0, a1);
            if (t + 2 < 32) {
                a0 = nt_load4(aP + (t + 2) * 32);
                a1 = nt_load4(aP + (t + 2) * 32 + 4);
            }
            COMPUTE(t + 1, c0, c1);
        }
#undef COMPUTE

        // QKV tile write. C/D: col(d)=lane&15 (+16j), row=(lane>>4)*4+reg.
        const int r0 = wv * 16 + lq * 4;
        #pragma unroll
        for (int r = 0; r < 4; ++r)
            QKV[(r0 + r) * 121 + k * 30 + lr] = acc0[r] + sbc[k * 32 + lr];
        const int d1 = 16 + lr;
        if (d1 < ((k == 0) ? 30 : 20)) {   // v only needed for head 0
            #pragma unroll
            for (int r = 0; r < 4; ++r)
                QKV[(r0 + r) * 121 + k * 30 + d1] = acc1[r] + sbc[k * 32 + d1];
        }
    }
    __syncthreads();   // QKV complete; Bs dead from here (sA overlays it)

    // ---------------- attention + heads epilogue (threads 0-127, 1 b-row each)
    float oc[10];
    if (tid < 128) {
        const float* Q = &QKV[tid * 121];
        float q[4][10], kk[4][10], v0[10];
        #pragma unroll
        for (int k = 0; k < 4; ++k)
            #pragma unroll
            for (int e = 0; e < 10; ++e) {
                q[k][e]  = Q[k * 30 + e];
                kk[k][e] = Q[k * 30 + 10 + e];
            }
        #pragma unroll
        for (int m = 0; m < 10; ++m) v0[m] = Q[20 + m];   // v, head 0

        float out0[10];
        #pragma unroll
        for (int e = 0; e < 10; ++e) out0[e] = 0.f;
        float* sAr = &sA[tid * 101];
        const float inv = 0.31622776601683794f;  // 1/sqrt(10)

        #pragma unroll
        for (int m = 0; m < 10; ++m) {
            float col[10]; float mx = -1e30f;
            #pragma unroll
            for (int e = 0; e < 10; ++e) {
                col[e] = (q[0][e]*kk[0][m] + q[1][e]*kk[1][m]
                        + q[2][e]*kk[2][m] + q[3][e]*kk[3][m]) * inv;
                mx = fmaxf(mx, col[e]);
            }
            float s = 0.f;
            #pragma unroll
            for (int e = 0; e < 10; ++e) { col[e] = __expf(col[e] - mx); s += col[e]; }
            const float r = 1.f / s;
            #pragma unroll
            for (int e = 0; e < 10; ++e) {
                const float a = col[e] * r;
                sAr[e * 10 + m] = a;
                out0[e] += a * v0[m];
            }
        }

        #pragma unroll
        for (int c = 0; c < 10; ++c) oc[c] = 0.f;
        #pragma unroll
        for (int k = 0; k < 4; ++k) {
            float lg[10]; float mx = -1e30f;
            #pragma unroll
            for (int c = 0; c < 10; ++c) {
                float s = sb[k * 10 + c];
                #pragma unroll
                for (int e = 0; e < 10; ++e) s += out0[e] * sW[(k * 10 + c) * 10 + e];
                lg[c] = s; mx = fmaxf(mx, s);
            }
            float s = 0.f;
            #pragma unroll
            for (int c = 0; c < 10; ++c) { lg[c] = __expf(lg[c] - mx); s += lg[c]; }
            const float r = 0.25f / s;
            #pragma unroll
            for (int c = 0; c < 10; ++c) oc[c] += lg[c] * r;
        }
    }

    // ---- coalesced attn writeback: 128 b x 100 = 12800 floats
    __syncthreads();
    const size_t abase = (size_t)blockIdx.x * 12800;
    for (int i = tid; i < 12800; i += 512) {
        const int bl = i / 100;
        attn[abase + i] = sA[bl * 101 + (i - bl * 100)];
    }

    // ---- coalesced outputs writeback: 128 b x 10 = 1280 floats
    __syncthreads();
    if (tid < 128) {
        #pragma unroll
        for (int c = 0; c < 10; ++c) sA[tid * 11 + c] = oc[c];
    }
    __syncthreads();
    const size_t obase = (size_t)blockIdx.x * 1280;
    for (int i = tid; i < 1280; i += 512) {
        const int bl = i / 10;
        outputs[obase + i] = sA[bl * 11 + (i - bl * 10)];
    }
}

extern "C" void kernel_launch(void* const* d_in, const int* in_sizes, int n_in,
                              void* d_out, int out_size, void* d_ws, size_t ws_size,
                              hipStream_t stream) {
    const float* w0   = (const float*)d_in[0];
    const float* w1   = (const float*)d_in[1];
    const float* w2   = (const float*)d_in[2];
    const float* w3   = (const float*)d_in[3];
    const float* Wlin = (const float*)d_in[4];
    const float* blin = (const float*)d_in[5];
    const float* Wq   = (const float*)d_in[6];
    const float* bq   = (const float*)d_in[7];
    const float* Wk   = (const float*)d_in[8];
    const float* bk   = (const float*)d_in[9];
    const float* Wv   = (const float*)d_in[10];
    const float* bv   = (const float*)d_in[11];
    const float* Wfin = (const float*)d_in[12];
    const float* bfin = (const float*)d_in[13];

    char* ws = (char*)d_ws;
    ushort* Wcomb16 = (ushort*)ws;                          // 256 KiB  [4][32][1024] f16
    float*  bcomb   = (float*)(ws + ((size_t)256 << 10));   // 512 B    [4][32]

    float* outputs = (float*)d_out;
    float* attn    = outputs + (size_t)B_ROWS * 10;

    k_prep<<<256, 128, 0, stream>>>(Wlin, blin, Wq, Wk, Wv, bq, bk, bv, Wcomb16, bcomb);
    k_all <<<256, 512, 0, stream>>>(w0, w1, w2, w3, Wcomb16, bcomb, Wfin, bfin, outputs, attn);
}